// Round 8
// baseline (135.103 us; speedup 1.0000x reference)
//
#include <hip/hip_runtime.h>

// UpsampleUpFIRDn (up=2, 4x4 FIR). Wave owns TWO adjacent input rows
// (ty0, ty0+1): loads 4 input rows (ty0-1..ty0+2) as float4/lane, computes
// two output row-pairs (2ty0..2ty0+3), stages each 1022-float pair in a
// wave-PRIVATE swizzled LDS buffer (no __syncthreads — wave-ordered LDS ops),
// then stores dense 16B-aligned dwordx4 (misaligned stores caused ~2x DRAM
// write amplification, fixed in round 6: 198->127us).
//
// Weight map: oy even -> row weights k[3][*] (top tap), k[1][*] (bottom);
//             oy odd  -> k[2][*], k[0][*]; cols likewise by ox parity.

typedef float v4f __attribute__((ext_vector_type(4)));

__device__ __forceinline__ int SW(int i) {   // XOR swizzle, bijective in [0,1024)
    return i ^ (((i >> 5) & 7) << 2);
}

__global__ __launch_bounds__(256) void up2_k4_pair2(
    const float* __restrict__ x, const float* __restrict__ kw,
    float* __restrict__ out)
{
    const int H = 256, W = 256, OW = 511;
    __shared__ float lds[4][1024];

    int t   = threadIdx.x;                    // lane 0..63
    int wv  = threadIdx.y;                    // wave 0..3
    int ty0 = blockIdx.y * 8 + wv * 2;        // even input row 0..254
    int bc  = blockIdx.z;
    float* buf = lds[wv];                     // wave-private

    const float4* k4 = (const float4*)kw;     // uniform -> SGPR loads
    float4 K0 = k4[0], K1 = k4[1], K2 = k4[2], K3 = k4[3];

    const float* xp = x + (size_t)bc * (H * W);

    // 4 independent row loads: rows ty0-1 .. ty0+2 (clamped)
    float4 A[4];
    #pragma unroll
    for (int i = 0; i < 4; ++i) {
        int rr = ty0 - 1 + i;
        rr = rr < 0 ? 0 : (rr > H - 1 ? H - 1 : rr);
        A[i] = ((const float4*)(xp + (size_t)rr * W))[t];
    }
    if (ty0 == 0) { A[0].x = A[0].y = A[0].z = A[0].w = 0.f; }  // pad row above

    float Lh[4], Rh[4];
    #pragma unroll
    for (int i = 0; i < 4; ++i) {
        Lh[i] = __shfl_up(A[i].w, 1);
        Rh[i] = __shfl_down(A[i].x, 1);  // lane63: garbage, never stored
        if (t == 0) Lh[i] = 0.f;
    }

    size_t plane = (size_t)bc * (511 * 511);

    #pragma unroll
    for (int pr = 0; pr < 2; ++pr) {
        int ty = ty0 + pr;
        float4 m = A[pr], z = A[pr + 1], p = A[pr + 2];
        float mL = Lh[pr], zL = Lh[pr + 1], pL = Lh[pr + 2];
        float mR = Rh[pr], zR = Rh[pr + 1], pR = Rh[pr + 2];

        float e[8], o[8];
        // even out-row (2ty): rows (ty-1 -> K3, ty -> K1)
        e[0] = K3.w*mL  + K3.y*m.x + K1.w*zL  + K1.y*z.x;
        e[1] = K3.z*m.x + K3.x*m.y + K1.z*z.x + K1.x*z.y;
        e[2] = K3.w*m.x + K3.y*m.y + K1.w*z.x + K1.y*z.y;
        e[3] = K3.z*m.y + K3.x*m.z + K1.z*z.y + K1.x*z.z;
        e[4] = K3.w*m.y + K3.y*m.z + K1.w*z.y + K1.y*z.z;
        e[5] = K3.z*m.z + K3.x*m.w + K1.z*z.z + K1.x*z.w;
        e[6] = K3.w*m.z + K3.y*m.w + K1.w*z.z + K1.y*z.w;
        e[7] = K3.z*m.w + K3.x*mR  + K1.z*z.w + K1.x*zR;
        // odd out-row (2ty+1): rows (ty -> K2, ty+1 -> K0)
        o[0] = K2.w*zL  + K2.y*z.x + K0.w*pL  + K0.y*p.x;
        o[1] = K2.z*z.x + K2.x*z.y + K0.z*p.x + K0.x*p.y;
        o[2] = K2.w*z.x + K2.y*z.y + K0.w*p.x + K0.y*p.y;
        o[3] = K2.z*z.y + K2.x*z.z + K0.z*p.y + K0.x*p.z;
        o[4] = K2.w*z.y + K2.y*z.z + K0.w*p.y + K0.y*p.z;
        o[5] = K2.z*z.z + K2.x*z.w + K0.z*p.z + K0.x*p.w;
        o[6] = K2.w*z.z + K2.y*z.w + K0.w*p.z + K0.y*p.w;
        o[7] = K2.z*z.w + K2.x*zR  + K0.z*p.w + K0.x*pR;

        // stage row-pair: region float r -> buf[SW(r)]. e:[8t..8t+7], o:[511+8t..]
        // (lane63 e[7] slot == region 511 is overwritten by lane0's o[0]: program
        //  order within the wave guarantees o-writes land after e-writes.)
        #pragma unroll
        for (int j = 0; j < 8; ++j) buf[SW(8 * t + j)] = e[j];
        #pragma unroll
        for (int j = 0; j < 8; ++j) buf[SW(511 + 8 * t + j)] = o[j];

        // no barrier: buffer is wave-private; lgkmcnt ordering covers RAW/WAR.

        size_t P = plane + (size_t)(2 * ty) * OW;   // region base (float idx)
        int h = (int)((4 - (P & 3)) & 3);           // head scalars to 16B-align
        int nvalid = (ty < H - 1) ? 1022 : 511;     // ty=255: no odd row

        if (t < h) out[P + t] = buf[SW(t)];

        #pragma unroll
        for (int q = 0; q < 4; ++q) {
            int base = h + 256 * q + 4 * t;
            float v0 = buf[SW(min(base,     1023))];
            float v1 = buf[SW(min(base + 1, 1023))];
            float v2 = buf[SW(min(base + 2, 1023))];
            float v3 = buf[SW(min(base + 3, 1023))];
            if (base + 3 < nvalid) {
                *(v4f*)(out + P + base) = (v4f){v0, v1, v2, v3};
            } else {
                if (base     < nvalid) out[P + base]     = v0;
                if (base + 1 < nvalid) out[P + base + 1] = v1;
                if (base + 2 < nvalid) out[P + base + 2] = v2;
            }
        }
    }
}

extern "C" void kernel_launch(void* const* d_in, const int* in_sizes, int n_in,
                              void* d_out, int out_size, void* d_ws, size_t ws_size,
                              hipStream_t stream) {
    const float* x = (const float*)d_in[0];
    const float* k = (const float*)d_in[1];
    float* out = (float*)d_out;

    const int H = 256, W = 256;
    int BC = in_sizes[0] / (H * W);   // 512

    dim3 block(64, 4, 1);             // 4 waves; each owns 2 input rows
    dim3 grid(1, H / 8, BC);          // (1, 32, 512)
    hipLaunchKernelGGL(up2_k4_pair2, grid, block, 0, stream, x, k, out);
}

// Round 9
// 129.064 us; speedup vs baseline: 1.0468x; 1.0468x over previous
//
#include <hip/hip_runtime.h>

// UpsampleUpFIRDn (up=2, 4x4 FIR). Wave-per-input-row (round 6 structure,
// best=127us), minus the block barrier (LDS buffers are wave-private), plus
// vectorized LDS reads: the staging layout is pre-shifted by the row-pair's
// global misalignment h so the cooperative store phase reads aligned
// ds_read_b128 groups. All global stores remain dense, 16B-aligned dwordx4
// (misaligned vector stores caused ~2x DRAM write amplification, round 3/6).
//
// Region = 1022 contiguous output floats (rows 2ty, 2ty+1). Float r of the
// region lives at buf[SW((r - h) & 1023)], h = alignment offset of region base.
//
// Weight map: oy even -> row weights k[3][*] (top tap), k[1][*] (bottom);
//             oy odd  -> k[2][*], k[0][*]; cols likewise by ox parity.

typedef float v4f __attribute__((ext_vector_type(4)));

__device__ __forceinline__ int SW(int i) {   // XOR swizzle, bijective in [0,1024)
    return i ^ (((i >> 5) & 7) << 2);
}

__global__ __launch_bounds__(256) void up2_k4_ldsv(
    const float* __restrict__ x, const float* __restrict__ kw,
    float* __restrict__ out)
{
    const int H = 256, W = 256, OW = 511;
    __shared__ float lds[4][1024];

    int t  = threadIdx.x;                     // lane 0..63
    int wv = threadIdx.y;                     // wave 0..3
    int ty = blockIdx.y * 4 + wv;             // input row 0..255
    int bc = blockIdx.z;
    float* buf = lds[wv];                     // wave-private

    const float4* k4 = (const float4*)kw;     // uniform -> SGPR loads
    float4 K0 = k4[0], K1 = k4[1], K2 = k4[2], K3 = k4[3];

    const float* xp = x + (size_t)bc * (H * W);
    int rm = (ty > 0) ? ty - 1 : 0;
    int rp = (ty < H - 1) ? ty + 1 : H - 1;
    float4 m = ((const float4*)(xp + (size_t)rm * W))[t];
    float4 z = ((const float4*)(xp + (size_t)ty * W))[t];
    float4 p = ((const float4*)(xp + (size_t)rp * W))[t];
    if (ty == 0) { m.x = m.y = m.z = m.w = 0.f; }

    float mL = __shfl_up(m.w, 1), zL = __shfl_up(z.w, 1), pL = __shfl_up(p.w, 1);
    float mR = __shfl_down(m.x, 1), zR = __shfl_down(z.x, 1), pR = __shfl_down(p.x, 1);
    if (t == 0) { mL = 0.f; zL = 0.f; pL = 0.f; }
    // lane 63: mR/zR/pR garbage -> e[7]/o[7] land in region slots >= 511+... that
    // are either overwritten by valid data or predicated off at store time.

    float e[8], o[8];
    // even out-row (2ty): rows (ty-1 -> K3, ty -> K1)
    e[0] = K3.w*mL  + K3.y*m.x + K1.w*zL  + K1.y*z.x;
    e[1] = K3.z*m.x + K3.x*m.y + K1.z*z.x + K1.x*z.y;
    e[2] = K3.w*m.x + K3.y*m.y + K1.w*z.x + K1.y*z.y;
    e[3] = K3.z*m.y + K3.x*m.z + K1.z*z.y + K1.x*z.z;
    e[4] = K3.w*m.y + K3.y*m.z + K1.w*z.y + K1.y*z.z;
    e[5] = K3.z*m.z + K3.x*m.w + K1.z*z.z + K1.x*z.w;
    e[6] = K3.w*m.z + K3.y*m.w + K1.w*z.z + K1.y*z.w;
    e[7] = K3.z*m.w + K3.x*mR  + K1.z*z.w + K1.x*zR;
    // odd out-row (2ty+1): rows (ty -> K2, ty+1 -> K0)
    o[0] = K2.w*zL  + K2.y*z.x + K0.w*pL  + K0.y*p.x;
    o[1] = K2.z*z.x + K2.x*z.y + K0.z*p.x + K0.x*p.y;
    o[2] = K2.w*z.x + K2.y*z.y + K0.w*p.x + K0.y*p.y;
    o[3] = K2.z*z.y + K2.x*z.z + K0.z*p.y + K0.x*p.z;
    o[4] = K2.w*z.y + K2.y*z.z + K0.w*p.y + K0.y*p.z;
    o[5] = K2.z*z.z + K2.x*z.w + K0.z*p.z + K0.x*p.w;
    o[6] = K2.w*z.z + K2.y*z.w + K0.w*p.z + K0.y*p.w;
    o[7] = K2.z*z.w + K2.x*zR  + K0.z*p.w + K0.x*pR;

    size_t plane = (size_t)bc * (511 * 511);
    size_t P = plane + (size_t)(2 * ty) * OW;   // region base (float idx)
    int h = (int)((4 - (P & 3)) & 3);           // head scalars to 16B-align
    int nvalid = (ty < H - 1) ? 1022 : 511;     // ty=255: no odd row

    // stage, pre-shifted by h: region float r -> buf[SW((r - h) & 1023)]
    #pragma unroll
    for (int j = 0; j < 8; ++j) buf[SW((8 * t + j - h) & 1023)] = e[j];
    #pragma unroll
    for (int j = 0; j < 8; ++j) buf[SW((511 + 8 * t + j - h) & 1023)] = o[j];

    // no barrier: buffer is wave-private; intra-wave lgkmcnt covers RAW.

    if (t < h) out[P + t] = buf[SW((1024 + t - h) & 1023)];  // head scalars

    #pragma unroll
    for (int q = 0; q < 4; ++q) {
        int base = h + 256 * q + 4 * t;           // region index of group start
        v4f v = *(const v4f*)(buf + SW(256 * q + 4 * t));  // aligned b128 read
        if (base + 3 < nvalid) {
            *(v4f*)(out + P + base) = v;
        } else {
            if (base     < nvalid) out[P + base]     = v.x;
            if (base + 1 < nvalid) out[P + base + 1] = v.y;
            if (base + 2 < nvalid) out[P + base + 2] = v.z;
        }
    }
}

extern "C" void kernel_launch(void* const* d_in, const int* in_sizes, int n_in,
                              void* d_out, int out_size, void* d_ws, size_t ws_size,
                              hipStream_t stream) {
    const float* x = (const float*)d_in[0];
    const float* k = (const float*)d_in[1];
    float* out = (float*)d_out;

    const int H = 256, W = 256;
    int BC = in_sizes[0] / (H * W);   // 512

    dim3 block(64, 4, 1);             // 4 waves; each owns one input row
    dim3 grid(1, H / 4, BC);          // (1, 64, 512)
    hipLaunchKernelGGL(up2_k4_ldsv, grid, block, 0, stream, x, k, out);
}

// Round 10
// 121.293 us; speedup vs baseline: 1.1139x; 1.0641x over previous
//
#include <hip/hip_runtime.h>

// UpsampleUpFIRDn (up=2, 4x4 FIR). Wave-per-input-row; outputs staged through
// wave-private swizzled LDS, then stored as dense 16B-aligned dwordx4 —
// NONTEMPORAL: write-once output should stream past L2 (fill kernel shows
// 7 TB/s pure-write). Round 3's nt-amplification was from MISALIGNED 8B nt
// stores (partial-sector RMW); aligned full-sector nt stores should be clean.
// Falsifier: WRITE_SIZE must stay 536550 KB.
//
// Region = 1022 contiguous output floats (rows 2ty, 2ty+1). Float r of the
// region lives at buf[SW((r - h) & 1023)], h = alignment offset of region base.
//
// Weight map: oy even -> row weights k[3][*] (top tap), k[1][*] (bottom);
//             oy odd  -> k[2][*], k[0][*]; cols likewise by ox parity.

typedef float v4f __attribute__((ext_vector_type(4)));

__device__ __forceinline__ int SW(int i) {   // XOR swizzle, bijective in [0,1024)
    return i ^ (((i >> 5) & 7) << 2);
}

__global__ __launch_bounds__(256) void up2_k4_nt(
    const float* __restrict__ x, const float* __restrict__ kw,
    float* __restrict__ out)
{
    const int H = 256, W = 256, OW = 511;
    __shared__ float lds[4][1024];

    int t  = threadIdx.x;                     // lane 0..63
    int wv = threadIdx.y;                     // wave 0..3
    int ty = blockIdx.y * 4 + wv;             // input row 0..255
    int bc = blockIdx.z;
    float* buf = lds[wv];                     // wave-private

    const float4* k4 = (const float4*)kw;     // uniform -> SGPR loads
    float4 K0 = k4[0], K1 = k4[1], K2 = k4[2], K3 = k4[3];

    const float* xp = x + (size_t)bc * (H * W);
    int rm = (ty > 0) ? ty - 1 : 0;
    int rp = (ty < H - 1) ? ty + 1 : H - 1;
    float4 m = ((const float4*)(xp + (size_t)rm * W))[t];
    float4 z = ((const float4*)(xp + (size_t)ty * W))[t];
    float4 p = ((const float4*)(xp + (size_t)rp * W))[t];
    if (ty == 0) { m.x = m.y = m.z = m.w = 0.f; }

    float mL = __shfl_up(m.w, 1), zL = __shfl_up(z.w, 1), pL = __shfl_up(p.w, 1);
    float mR = __shfl_down(m.x, 1), zR = __shfl_down(z.x, 1), pR = __shfl_down(p.x, 1);
    if (t == 0) { mL = 0.f; zL = 0.f; pL = 0.f; }
    // lane 63: mR/zR/pR garbage -> e[7]/o[7] land in slots overwritten by valid
    // data (e[7] slot <- lane0 o[0], program order) or predicated off at store.

    float e[8], o[8];
    // even out-row (2ty): rows (ty-1 -> K3, ty -> K1)
    e[0] = K3.w*mL  + K3.y*m.x + K1.w*zL  + K1.y*z.x;
    e[1] = K3.z*m.x + K3.x*m.y + K1.z*z.x + K1.x*z.y;
    e[2] = K3.w*m.x + K3.y*m.y + K1.w*z.x + K1.y*z.y;
    e[3] = K3.z*m.y + K3.x*m.z + K1.z*z.y + K1.x*z.z;
    e[4] = K3.w*m.y + K3.y*m.z + K1.w*z.y + K1.y*z.z;
    e[5] = K3.z*m.z + K3.x*m.w + K1.z*z.z + K1.x*z.w;
    e[6] = K3.w*m.z + K3.y*m.w + K1.w*z.z + K1.y*z.w;
    e[7] = K3.z*m.w + K3.x*mR  + K1.z*z.w + K1.x*zR;
    // odd out-row (2ty+1): rows (ty -> K2, ty+1 -> K0)
    o[0] = K2.w*zL  + K2.y*z.x + K0.w*pL  + K0.y*p.x;
    o[1] = K2.z*z.x + K2.x*z.y + K0.z*p.x + K0.x*p.y;
    o[2] = K2.w*z.x + K2.y*z.y + K0.w*p.x + K0.y*p.y;
    o[3] = K2.z*z.y + K2.x*z.z + K0.z*p.y + K0.x*p.z;
    o[4] = K2.w*z.y + K2.y*z.z + K0.w*p.y + K0.y*p.z;
    o[5] = K2.z*z.z + K2.x*z.w + K0.z*p.z + K0.x*p.w;
    o[6] = K2.w*z.z + K2.y*z.w + K0.w*p.z + K0.y*p.w;
    o[7] = K2.z*z.w + K2.x*zR  + K0.z*p.w + K0.x*pR;

    size_t plane = (size_t)bc * (511 * 511);
    size_t P = plane + (size_t)(2 * ty) * OW;   // region base (float idx)
    int h = (int)((4 - (P & 3)) & 3);           // head scalars to 16B-align
    int nvalid = (ty < H - 1) ? 1022 : 511;     // ty=255: no odd row

    // stage, pre-shifted by h: region float r -> buf[SW((r - h) & 1023)]
    #pragma unroll
    for (int j = 0; j < 8; ++j) buf[SW((8 * t + j - h) & 1023)] = e[j];
    #pragma unroll
    for (int j = 0; j < 8; ++j) buf[SW((511 + 8 * t + j - h) & 1023)] = o[j];

    // no barrier: buffer is wave-private; intra-wave lgkmcnt covers RAW.

    if (t < h) out[P + t] = buf[SW((1024 + t - h) & 1023)];  // head scalars

    #pragma unroll
    for (int q = 0; q < 4; ++q) {
        int base = h + 256 * q + 4 * t;           // region index of group start
        v4f v = *(const v4f*)(buf + SW(256 * q + 4 * t));  // aligned b128 read
        if (base + 3 < nvalid) {
            __builtin_nontemporal_store(v, (v4f*)(out + P + base));
        } else {
            if (base     < nvalid) out[P + base]     = v.x;
            if (base + 1 < nvalid) out[P + base + 1] = v.y;
            if (base + 2 < nvalid) out[P + base + 2] = v.z;
        }
    }
}

extern "C" void kernel_launch(void* const* d_in, const int* in_sizes, int n_in,
                              void* d_out, int out_size, void* d_ws, size_t ws_size,
                              hipStream_t stream) {
    const float* x = (const float*)d_in[0];
    const float* k = (const float*)d_in[1];
    float* out = (float*)d_out;

    const int H = 256, W = 256;
    int BC = in_sizes[0] / (H * W);   // 512

    dim3 block(64, 4, 1);             // 4 waves; each owns one input row
    dim3 grid(1, H / 4, BC);          // (1, 64, 512)
    hipLaunchKernelGGL(up2_k4_nt, grid, block, 0, stream, x, k, out);
}